// Round 1
// baseline (76.770 us; speedup 1.0000x reference)
//
#include <hip/hip_runtime.h>

#define NB   8
#define NIN  512
#define TOUT 4096
#define ND   384

// Kernel 1: per-batch scan of ds -> token-index map idx[b][t] (-1 = empty)
__global__ __launch_bounds__(NIN) void build_idx(const int* __restrict__ ds,
                                                 int* __restrict__ idx) {
    const int b   = blockIdx.x;
    const int tid = threadIdx.x;           // 0..511
    __shared__ int s[NIN];

    const int d = ds[b * NIN + tid];
    s[tid] = d;

    // init this batch's idx map to -1 (global writes, ordered vs. the
    // scatter below by the __syncthreads barriers in the scan)
    #pragma unroll
    for (int t = tid; t < TOUT; t += NIN) idx[b * TOUT + t] = -1;
    __syncthreads();

    // Hillis-Steele inclusive scan over 512 elements
    #pragma unroll
    for (int off = 1; off < NIN; off <<= 1) {
        int v = (tid >= off) ? s[tid - off] : 0;
        __syncthreads();
        s[tid] += v;
        __syncthreads();
    }

    int right = s[tid];
    int left  = right - d;
    if (right > TOUT) right = TOUT;
    for (int t = left; t < right; ++t) idx[b * TOUT + t] = tid;
}

// Kernel 2: one thread per output float4. out[b,t,:] = idx>=0 ? xs[b,idx,:] : 0
__global__ __launch_bounds__(256) void gather(const float4* __restrict__ xs,
                                              const int* __restrict__ idx,
                                              float4* __restrict__ out) {
    const int J = ND / 4;  // 96 float4 per row
    unsigned gid = blockIdx.x * blockDim.x + threadIdx.x;  // < 3,145,728
    unsigned j   = gid % J;
    unsigned row = gid / J;          // b*TOUT + t, < 32768
    int i = idx[row];                // row-broadcast load, cache-hit
    float4 v = make_float4(0.f, 0.f, 0.f, 0.f);
    if (i >= 0) {
        unsigned b = row / TOUT;
        v = xs[(b * NIN + (unsigned)i) * J + j];
    }
    out[(unsigned long)row * J + j] = v;
}

extern "C" void kernel_launch(void* const* d_in, const int* in_sizes, int n_in,
                              void* d_out, int out_size, void* d_ws, size_t ws_size,
                              hipStream_t stream) {
    const float* xs = (const float*)d_in[0];   // (8, 512, 384) f32
    const int*   ds = (const int*)d_in[1];     // (8, 512) int
    float* out = (float*)d_out;                // (8, 4096, 384) f32
    int* idx = (int*)d_ws;                     // NB*TOUT ints = 128 KB

    build_idx<<<NB, NIN, 0, stream>>>(ds, idx);

    const unsigned total4 = NB * TOUT * (ND / 4);   // 3,145,728 float4
    gather<<<total4 / 256, 256, 0, stream>>>((const float4*)xs, idx,
                                             (float4*)out);
}

// Round 3
// 75.481 us; speedup vs baseline: 1.0171x; 1.0171x over previous
//
#include <hip/hip_runtime.h>

#define NB    8
#define NIN   512
#define TOUT  4096
#define ND    384
#define J4    (ND / 4)     // 96 float4 per row
#define TROWS 32           // output rows per block
#define BLK   256          // threads per block (4 waves)

// One fused kernel: per-block redundant scan of ds[b] (2 KB, L2-hit),
// binary-search owner token per output row, coalesced float4 stores.
__global__ __launch_bounds__(BLK) void lenreg(const float4* __restrict__ xs,
                                              const int* __restrict__ ds,
                                              float4* __restrict__ out) {
    const int b       = blockIdx.y;               // batch 0..7
    const int rowbase = blockIdx.x * TROWS;       // first output frame
    const int tid     = threadIdx.x;

    __shared__ int cum[NIN];        // inclusive scan of ds[b]
    __shared__ int wsum[BLK / 64];  // per-wave scan totals
    __shared__ int owner[TROWS];    // owning token per row (-1 = empty)

    // ---- Phase A: inclusive scan of ds[b][0..511] (each thread 2 elems) ----
    const int* dsb = ds + b * NIN;
    const int a0 = dsb[2 * tid];
    const int a1 = dsb[2 * tid + 1];
    int p = a0 + a1;                // pair sum
    const int lane = tid & 63;
    const int wid  = tid >> 6;
    #pragma unroll
    for (int off = 1; off < 64; off <<= 1) {
        int v = __shfl_up(p, off, 64);
        if (lane >= off) p += v;
    }
    if (lane == 63) wsum[wid] = p;
    __syncthreads();
    int acc = 0;
    #pragma unroll
    for (int w = 0; w < BLK / 64; ++w)
        if (w < wid) acc += wsum[w];
    p += acc;                       // inclusive scan of pair sums
    cum[2 * tid + 1] = p;
    cum[2 * tid]     = p - a1;
    __syncthreads();

    // ---- Phase B: owner token for each of this block's TROWS rows ----
    const int total = cum[NIN - 1];
    if (tid < TROWS) {
        const int t = rowbase + tid;
        int o = -1;
        if (t < total) {            // lower_bound: smallest i with cum[i] > t
            int lo = 0, hi = NIN;
            // 10 guarded steps: range 512 needs ceil(log2(512))+1 = 10 to
            // guarantee hi-lo==0 (9 steps can leave hi-lo==1, index lo
            // untested -> off-by-one owner, the R2 bug). Guard prevents
            // OOB cum[512] on converged lanes.
            #pragma unroll
            for (int s = 0; s < 10; ++s) {
                if (lo < hi) {
                    int mid = (lo + hi) >> 1;
                    if (cum[mid] > t) hi = mid; else lo = mid + 1;
                }
            }
            o = lo;                 // zero-length tokens skipped automatically
        }
        owner[tid] = o;
    }
    __syncthreads();

    // ---- Phase C: stream TROWS rows of float4, fully coalesced ----
    const float4* xsb  = xs + (size_t)b * NIN * J4;
    float4*       outb = out + ((size_t)b * TOUT + rowbase) * J4;
    #pragma unroll
    for (int k = 0; k < TROWS * J4 / BLK; ++k) {   // 12 iterations
        const int g = k * BLK + tid;               // 0..3071
        const int r = g / J4;                      // row within tile
        const int j = g - r * J4;                  // float4 within row
        const int o = owner[r];
        float4 v = make_float4(0.f, 0.f, 0.f, 0.f);
        if (o >= 0) v = xsb[o * J4 + j];
        outb[g] = v;
    }
}

extern "C" void kernel_launch(void* const* d_in, const int* in_sizes, int n_in,
                              void* d_out, int out_size, void* d_ws, size_t ws_size,
                              hipStream_t stream) {
    const float* xs = (const float*)d_in[0];   // (8, 512, 384) f32
    const int*   ds = (const int*)d_in[1];     // (8, 512) int
    float* out = (float*)d_out;                // (8, 4096, 384) f32

    dim3 grid(TOUT / TROWS, NB);               // 128 x 8 = 1024 blocks
    lenreg<<<grid, BLK, 0, stream>>>((const float4*)xs, ds, (float4*)out);
}

// Round 4
// 75.272 us; speedup vs baseline: 1.0199x; 1.0028x over previous
//
#include <hip/hip_runtime.h>

#define NB    8
#define NIN   512
#define TOUT  4096
#define ND    384
#define J4    (ND / 4)     // 96 float4 per row
#define TROWS 32           // output rows per block
#define BLK   256          // threads per block (4 waves)

// One fused kernel: per-block redundant scan of ds[b] (2 KB, L2-hit),
// binary-search owner token per output row, coalesced float4 stores.
// XCD swizzle: batch = blockIdx.x & 7 == XCD id (round-robin dispatch),
// so each XCD's private L2 only caches its own batch's 786 KB xs slice.
__global__ __launch_bounds__(BLK) void lenreg(const float4* __restrict__ xs,
                                              const int* __restrict__ ds,
                                              float4* __restrict__ out) {
    const int b       = blockIdx.x & 7;             // batch -> XCD pin
    const int rowbase = (blockIdx.x >> 3) * TROWS;  // first output frame
    const int tid     = threadIdx.x;

    __shared__ int cum[NIN];        // inclusive scan of ds[b]
    __shared__ int wsum[BLK / 64];  // per-wave scan totals
    __shared__ int owner[TROWS];    // owning token per row (-1 = empty)

    // ---- Phase A: inclusive scan of ds[b][0..511] (each thread 2 elems) ----
    const int* dsb = ds + b * NIN;
    const int a0 = dsb[2 * tid];
    const int a1 = dsb[2 * tid + 1];
    int p = a0 + a1;                // pair sum
    const int lane = tid & 63;
    const int wid  = tid >> 6;
    #pragma unroll
    for (int off = 1; off < 64; off <<= 1) {
        int v = __shfl_up(p, off, 64);
        if (lane >= off) p += v;
    }
    if (lane == 63) wsum[wid] = p;
    __syncthreads();
    int acc = 0;
    #pragma unroll
    for (int w = 0; w < BLK / 64; ++w)
        if (w < wid) acc += wsum[w];
    p += acc;                       // inclusive scan of pair sums
    cum[2 * tid + 1] = p;
    cum[2 * tid]     = p - a1;
    __syncthreads();

    // ---- Phase B: owner token for each of this block's TROWS rows ----
    const int total = cum[NIN - 1];
    if (tid < TROWS) {
        const int t = rowbase + tid;
        int o = -1;
        if (t < total) {            // lower_bound: smallest i with cum[i] > t
            int lo = 0, hi = NIN;
            // 10 guarded steps (range 512): 9 can leave hi-lo==1 untested.
            #pragma unroll
            for (int s = 0; s < 10; ++s) {
                if (lo < hi) {
                    int mid = (lo + hi) >> 1;
                    if (cum[mid] > t) hi = mid; else lo = mid + 1;
                }
            }
            o = lo;                 // zero-length tokens skipped automatically
        }
        owner[tid] = o;
    }
    __syncthreads();

    // ---- Phase C: stream TROWS rows of float4, fully coalesced ----
    const float4* xsb  = xs + (size_t)b * NIN * J4;
    float4*       outb = out + ((size_t)b * TOUT + rowbase) * J4;
    #pragma unroll
    for (int k = 0; k < TROWS * J4 / BLK; ++k) {   // 12 iterations
        const int g = k * BLK + tid;               // 0..3071
        const int r = g / J4;                      // row within tile
        const int j = g - r * J4;                  // float4 within row
        const int o = owner[r];
        float4 v = make_float4(0.f, 0.f, 0.f, 0.f);
        if (o >= 0) v = xsb[o * J4 + j];
        outb[g] = v;
    }
}

extern "C" void kernel_launch(void* const* d_in, const int* in_sizes, int n_in,
                              void* d_out, int out_size, void* d_ws, size_t ws_size,
                              hipStream_t stream) {
    const float* xs = (const float*)d_in[0];   // (8, 512, 384) f32
    const int*   ds = (const int*)d_in[1];     // (8, 512) int
    float* out = (float*)d_out;                // (8, 4096, 384) f32

    // 1D grid: low 3 bits = batch = XCD slot, high bits = row tile
    lenreg<<<(TOUT / TROWS) * NB, BLK, 0, stream>>>((const float4*)xs, ds,
                                                    (float4*)out);
}